// Round 11
// baseline (42.110 us; speedup 1.0000x reference)
//
#include <hip/hip_runtime.h>

// Problem constants (fixed by the reference)
#define NXY   16
#define NZ    8
#define NS    2048      // states = 16*16*8
#define NT    2048      // tokens
#define NB    16        // stories
#define NL    16        // story length
#define NSENT 16        // tokens per sentence
#define NEGV  (-1e9f)

// ---------------------------------------------------------------------------
// K0: weight-table prep (round-10 proven). One thread per (slot, state);
// the scattered trans gather runs once with full-chip TLP.
// ---------------------------------------------------------------------------
__global__ __launch_bounds__(256) void k_prep(const float* __restrict__ trans,
                                              float* __restrict__ wtab) {
    const int g = blockIdx.x * 256 + threadIdx.x;      // [0, 7*NS)
    if (g >= 7 * NS) return;
    const int k = g >> 11;           // neighbor slot 0..6
    const int h = g & (NS - 1);      // state
    const int x = h & 15, y = (h >> 4) & 15, z = h >> 8;
    const float* row = trans + (size_t)h * NS;
    float w;
    switch (k) {
        case 0: w = row[h]; break;
        case 1: w = (x < 15) ? row[h + 1]   : NEGV; break;
        case 2: w = (x > 0)  ? row[h - 1]   : NEGV; break;
        case 3: w = (y < 15) ? row[h + 16]  : NEGV; break;
        case 4: w = (y > 0)  ? row[h - 16]  : NEGV; break;
        case 5: w = (z < 7)  ? row[h + 256] : NEGV; break;
        default: w = (z < 6) ? row[h + 512] : NEGV; break;
    }
    wtab[g] = w;
}

// ---------------------------------------------------------------------------
// K1 v2: fused smoothing + transpose, register x-pass (round-6 proven body).
// ---------------------------------------------------------------------------
#define TT   16
#define SPAD 17

__global__ __launch_bounds__(256) void k_smooth(const float* __restrict__ em,
                                                float* __restrict__ emT) {
    __shared__ float S[256 * SPAD];   // 17408 B
    const int tid = threadIdx.x;
    const int t0 = blockIdx.x * TT;
    const int z = blockIdx.y;
    const int toff = tid & 15, y = tid >> 4;

    const float* base = em + ((size_t)z * 256 + y * 16) * NT + t0 + toff;
    float ex[16];
#pragma unroll
    for (int x = 0; x < 16; ++x)
        ex[x] = __expf(base[(size_t)x * NT]);

#pragma unroll
    for (int x = 0; x < 16; ++x) {
        const int xm2 = x - 2 < 0 ? 0 : x - 2, xm1 = x - 1 < 0 ? 0 : x - 1;
        const int xp1 = x + 1 > 15 ? 15 : x + 1, xp2 = x + 2 > 15 ? 15 : x + 2;
        S[(y * 16 + x) * SPAD + toff] = ex[xm2] + ex[xm1] + ex[x] + ex[xp1] + ex[xp2];
    }
    __syncthreads();

    const int x2 = tid & 15, y2 = tid >> 4;
    int ry[5];
#pragma unroll
    for (int k = 0; k < 5; ++k) {
        int yy = y2 + k - 2; yy = yy < 0 ? 0 : (yy > 15 ? 15 : yy);
        ry[k] = (yy * 16 + x2) * SPAD;
    }
    const float LOG25 = 3.2188758248682006f;   // log(5)+log(5)
    float* ob = emT + (size_t)t0 * NS + z * 256 + tid;
#pragma unroll
    for (int t = 0; t < TT; ++t) {
        float a = S[ry[0] + t] + S[ry[1] + t] + S[ry[2] + t] + S[ry[3] + t] + S[ry[4] + t];
        ob[(size_t)t * NS] = __logf(a) - LOG25;
    }
}

// ---------------------------------------------------------------------------
// K2: e_all[b,l,s] = sum_j em_T[tok[b,l,j], s]   (round-2 proven, unchanged)
// ---------------------------------------------------------------------------
__global__ __launch_bounds__(256) void k_eall(const int* __restrict__ stories,
                                              const float* __restrict__ emT,
                                              float* __restrict__ eall) {
    const int bl = blockIdx.x;
    const int col = blockIdx.y * 256 + threadIdx.x;
    __shared__ int toks[NSENT];
    if (threadIdx.x < NSENT) toks[threadIdx.x] = stories[bl * NSENT + threadIdx.x];
    __syncthreads();

    float4 a = make_float4(0.f, 0.f, 0.f, 0.f);
#pragma unroll 4
    for (int j = 0; j < NSENT; ++j) {
        float4 v = ((const float4*)(emT + (size_t)toks[j] * NS))[col];
        a.x += v.x; a.y += v.y; a.z += v.z; a.w += v.w;
    }
    ((float4*)(eall + (size_t)bl * NS))[col] = a;
}

// ---------------------------------------------------------------------------
// K3 v5: forward recursion; round-10 body but the in-loop __syncthreads()
// (which compiles to s_waitcnt vmcnt(0) lgkmcnt(0) + s_barrier, draining the
// in-flight out-store and e-prefetch EVERY step) is replaced by a raw
// barrier that orders ONLY LDS:
//     ds_write -> sched_barrier -> s_waitcnt lgkmcnt(0) -> s_barrier
//     -> sched_barrier
// Each wave's cur-write is retired before it signals the barrier, so all
// writes are visible after it. Global stores become fire-and-forget
// (drained once at kernel end); e-loads wait on use only.
// ---------------------------------------------------------------------------
#define FPAD_F 16
#define FPAD_B 512

__global__ __launch_bounds__(1024) void k_forward(const float* __restrict__ wtab,
                                                  const float* __restrict__ priors,
                                                  const float* __restrict__ eall,
                                                  float* __restrict__ out) {
    __shared__ float rawA[FPAD_F + NS + FPAD_B];   // 10.3 KB each
    __shared__ float rawB[FPAD_F + NS + FPAD_B];
    float* A = rawA + FPAD_F;
    float* Bv = rawB + FPAD_F;

    const int b = blockIdx.x;
    const int tid = threadIdx.x;
    const int h0 = tid * 2;                        // even state; h1 = h0+1

    // zero the guard pads (finite junk; NEGV weights kill their contribution)
    for (int i = tid; i < FPAD_F + FPAD_B; i += 1024) {
        int idx = (i < FPAD_F) ? i : FPAD_F + NS + (i - FPAD_F);
        rawA[idx] = 0.f;
        rawB[idx] = 0.f;
    }

    // weights for the state pair: w[k].x -> state h0, w[k].y -> state h1
    float2 w[7];
#pragma unroll
    for (int k = 0; k < 7; ++k)
        w[k] = *(const float2*)(wtab + (size_t)k * NS + h0);

    const float* eb = eall + (size_t)b * NL * NS;
    float2 e0 = *(const float2*)(eb + h0);
    float2 pr = *(const float2*)(priors + h0);
    float2 vres = make_float2(e0.x + pr.x, e0.y + pr.y);
    *(float2*)(A + h0) = vres;
    float2 e_cur = *(const float2*)(eb + NS + h0);   // e for l=1
    __syncthreads();                                 // full drain ONCE

    float* prev = A;
    float* cur = Bv;
    for (int l = 1; l < NL; ++l) {
        // fire-and-forget store of step l-1's result (never drained in-loop)
        *(float2*)(out + ((size_t)(l - 1) * NB + b) * NS + h0) = vres;
        // prefetch next step's e pair (waited on use, next iteration)
        float2 e_nxt = make_float2(0.f, 0.f);
        if (l + 1 < NL) e_nxt = *(const float2*)(eb + (size_t)(l + 1) * NS + h0);

        // 7 vectorized LDS reads cover both states' 7-neighbor sets
        float2 c0 = *(const float2*)(prev + h0);          // prev[h0], prev[h0+1]
        float  xl = prev[h0 - 1];
        float  xr = prev[h0 + 2];
        float2 ym = *(const float2*)(prev + h0 - 16);
        float2 yp = *(const float2*)(prev + h0 + 16);
        float2 z1 = *(const float2*)(prev + h0 + 256);
        float2 z2 = *(const float2*)(prev + h0 + 512);

        // state h0: self=c0.x, x+1=c0.y, x-1=xl, y+-16, z+256, z+512
        float a0 = w[0].x + c0.x, a1 = w[1].x + c0.y, a2 = w[2].x + xl;
        float a3 = w[3].x + yp.x, a4 = w[4].x + ym.x, a5 = w[5].x + z1.x, a6 = w[6].x + z2.x;
        float m0 = fmaxf(fmaxf(fmaxf(a0, a1), fmaxf(a2, a3)),
                         fmaxf(fmaxf(a4, a5), a6));
        float s0 = __expf(a0 - m0) + __expf(a1 - m0) + __expf(a2 - m0) + __expf(a3 - m0) +
                   __expf(a4 - m0) + __expf(a5 - m0) + __expf(a6 - m0);
        // state h1: self=c0.y, x+1=xr, x-1=c0.x
        float b0 = w[0].y + c0.y, b1 = w[1].y + xr, b2 = w[2].y + c0.x;
        float b3 = w[3].y + yp.y, b4 = w[4].y + ym.y, b5 = w[5].y + z1.y, b6 = w[6].y + z2.y;
        float m1 = fmaxf(fmaxf(fmaxf(b0, b1), fmaxf(b2, b3)),
                         fmaxf(fmaxf(b4, b5), b6));
        float s1 = __expf(b0 - m1) + __expf(b1 - m1) + __expf(b2 - m1) + __expf(b3 - m1) +
                   __expf(b4 - m1) + __expf(b5 - m1) + __expf(b6 - m1);

        vres = make_float2(e_cur.x + m0 + __logf(s0), e_cur.y + m1 + __logf(s1));
        *(float2*)(cur + h0) = vres;

        // LDS-only barrier: my ds_write retired -> signal -> all writes visible
        __builtin_amdgcn_sched_barrier(0);
        asm volatile("s_waitcnt lgkmcnt(0)" ::: "memory");
        __builtin_amdgcn_s_barrier();
        __builtin_amdgcn_sched_barrier(0);

        e_cur = e_nxt;
        float* tmp = prev; prev = cur; cur = tmp;
    }

    // final step's result
    *(float2*)(out + ((size_t)(NL - 1) * NB + b) * NS + h0) = vres;
}

// ---------------------------------------------------------------------------
extern "C" void kernel_launch(void* const* d_in, const int* in_sizes, int n_in,
                              void* d_out, int out_size, void* d_ws, size_t ws_size,
                              hipStream_t stream) {
    (void)in_sizes; (void)n_in; (void)out_size; (void)ws_size;
    const int* stories  = (const int*)d_in[0];
    // d_in[1] = story_length (== NL), unused
    const float* priors = (const float*)d_in[2];
    const float* trans  = (const float*)d_in[3];
    const float* em     = (const float*)d_in[4];
    float* out = (float*)d_out;

    float* emT  = (float*)d_ws;                    // [NT][NS]    16 MB
    float* eall = emT + (size_t)NT * NS;           // [NB*NL][NS]  2 MB
    float* wtab = eall + (size_t)NB * NL * NS;     // [7][NS]     57 KB

    k_prep<<<dim3((7 * NS + 255) / 256), 256, 0, stream>>>(trans, wtab);
    k_smooth<<<dim3(NT / TT, NZ), 256, 0, stream>>>(em, emT);
    k_eall<<<dim3(NB * NL, 2), 256, 0, stream>>>(stories, emT, eall);
    k_forward<<<dim3(NB), 1024, 0, stream>>>(wtab, priors, eall, out);
}

// Round 12
// 39.158 us; speedup vs baseline: 1.0754x; 1.0754x over previous
//
#include <hip/hip_runtime.h>

// Problem constants (fixed by the reference)
#define NXY   16
#define NZ    8
#define NS    2048      // states = 16*16*8
#define NT    2048      // tokens
#define NB    16        // stories
#define NL    16        // story length
#define NSENT 16        // tokens per sentence
#define NEGV  (-1e9f)

// ---------------------------------------------------------------------------
// K1 v3: fused smoothing + transpose (round-6 proven body) PLUS the wtab
// prep (round-10 proven body) as extra grid blocks (blockIdx.y == 8).
// One dispatch fewer; prep's ~1MB scattered gather hides under smooth.
// ---------------------------------------------------------------------------
#define TT   16
#define SPAD 17

__global__ __launch_bounds__(256) void k_smooth(const float* __restrict__ em,
                                                float* __restrict__ emT,
                                                const float* __restrict__ trans,
                                                float* __restrict__ wtab) {
    const int tid = threadIdx.x;

    if (blockIdx.y == NZ) {
        // ---- prep path: one thread per (neighbor-slot, state)
        const int g = blockIdx.x * 256 + tid;          // [0, 32768)
        if (g < 7 * NS) {
            const int k = g >> 11;
            const int h = g & (NS - 1);
            const int x = h & 15, y = (h >> 4) & 15, z = h >> 8;
            const float* row = trans + (size_t)h * NS;
            float w;
            switch (k) {
                case 0: w = row[h]; break;
                case 1: w = (x < 15) ? row[h + 1]   : NEGV; break;
                case 2: w = (x > 0)  ? row[h - 1]   : NEGV; break;
                case 3: w = (y < 15) ? row[h + 16]  : NEGV; break;
                case 4: w = (y > 0)  ? row[h - 16]  : NEGV; break;
                case 5: w = (z < 7)  ? row[h + 256] : NEGV; break;
                default: w = (z < 6) ? row[h + 512] : NEGV; break;
            }
            wtab[g] = w;
        }
        return;
    }

    // ---- smooth path (round-6 body, unchanged)
    __shared__ float S[256 * SPAD];   // 17408 B
    const int t0 = blockIdx.x * TT;
    const int z = blockIdx.y;
    const int toff = tid & 15, y = tid >> 4;

    const float* base = em + ((size_t)z * 256 + y * 16) * NT + t0 + toff;
    float ex[16];
#pragma unroll
    for (int x = 0; x < 16; ++x)
        ex[x] = __expf(base[(size_t)x * NT]);

#pragma unroll
    for (int x = 0; x < 16; ++x) {
        const int xm2 = x - 2 < 0 ? 0 : x - 2, xm1 = x - 1 < 0 ? 0 : x - 1;
        const int xp1 = x + 1 > 15 ? 15 : x + 1, xp2 = x + 2 > 15 ? 15 : x + 2;
        S[(y * 16 + x) * SPAD + toff] = ex[xm2] + ex[xm1] + ex[x] + ex[xp1] + ex[xp2];
    }
    __syncthreads();

    const int x2 = tid & 15, y2 = tid >> 4;
    int ry[5];
#pragma unroll
    for (int k = 0; k < 5; ++k) {
        int yy = y2 + k - 2; yy = yy < 0 ? 0 : (yy > 15 ? 15 : yy);
        ry[k] = (yy * 16 + x2) * SPAD;
    }
    const float LOG25 = 3.2188758248682006f;   // log(5)+log(5)
    float* ob = emT + (size_t)t0 * NS + z * 256 + tid;
#pragma unroll
    for (int t = 0; t < TT; ++t) {
        float a = S[ry[0] + t] + S[ry[1] + t] + S[ry[2] + t] + S[ry[3] + t] + S[ry[4] + t];
        ob[(size_t)t * NS] = __logf(a) - LOG25;
    }
}

// ---------------------------------------------------------------------------
// K2: e_all[b,l,s] = sum_j em_T[tok[b,l,j], s]   (round-2 proven, unchanged)
// ---------------------------------------------------------------------------
__global__ __launch_bounds__(256) void k_eall(const int* __restrict__ stories,
                                              const float* __restrict__ emT,
                                              float* __restrict__ eall) {
    const int bl = blockIdx.x;
    const int col = blockIdx.y * 256 + threadIdx.x;
    __shared__ int toks[NSENT];
    if (threadIdx.x < NSENT) toks[threadIdx.x] = stories[bl * NSENT + threadIdx.x];
    __syncthreads();

    float4 a = make_float4(0.f, 0.f, 0.f, 0.f);
#pragma unroll 4
    for (int j = 0; j < NSENT; ++j) {
        float4 v = ((const float4*)(emT + (size_t)toks[j] * NS))[col];
        a.x += v.x; a.y += v.y; a.z += v.z; a.w += v.w;
    }
    ((float4*)(eall + (size_t)bl * NS))[col] = a;
}

// ---------------------------------------------------------------------------
// K3 v6: forward recursion, 512 threads x QUAD of states (4t..4t+3):
//   - LDS ops per step HALVED vs v5: 5 x ds_read_b128 + 2 x b32 per thread
//     (self-quad, y+-16 quads, z+256/z+512 quads, two x-edge scalars).
//   - 8 waves instead of 16 -> cheaper barrier, half the issue pressure.
//   - same exact lse7 math, guard-padded buffers, float4 wtab weights,
//     fire-and-forget out stores, lgkmcnt-only in-loop barrier.
// ---------------------------------------------------------------------------
#define FPAD_F 16
#define FPAD_B 512

__device__ __forceinline__ float lse7(float a0, float a1, float a2, float a3,
                                      float a4, float a5, float a6) {
    float m = fmaxf(fmaxf(fmaxf(a0, a1), fmaxf(a2, a3)),
                    fmaxf(fmaxf(a4, a5), a6));
    float s = __expf(a0 - m) + __expf(a1 - m) + __expf(a2 - m) + __expf(a3 - m) +
              __expf(a4 - m) + __expf(a5 - m) + __expf(a6 - m);
    return m + __logf(s);
}

__global__ __launch_bounds__(512) void k_forward(const float* __restrict__ wtab,
                                                 const float* __restrict__ priors,
                                                 const float* __restrict__ eall,
                                                 float* __restrict__ out) {
    __shared__ float rawA[FPAD_F + NS + FPAD_B];   // 10.3 KB each
    __shared__ float rawB[FPAD_F + NS + FPAD_B];
    float* A = rawA + FPAD_F;
    float* Bv = rawB + FPAD_F;

    const int b = blockIdx.x;
    const int tid = threadIdx.x;
    const int h0 = tid * 4;                        // quad base state

    // zero the guard pads (finite junk; NEGV weights kill their contribution)
    for (int i = tid; i < FPAD_F + FPAD_B; i += 512) {
        int idx = (i < FPAD_F) ? i : FPAD_F + NS + (i - FPAD_F);
        rawA[idx] = 0.f;
        rawB[idx] = 0.f;
    }

    // weights for the quad: w[k].{x,y,z,w} -> states h0..h0+3
    float4 w[7];
#pragma unroll
    for (int k = 0; k < 7; ++k)
        w[k] = *(const float4*)(wtab + (size_t)k * NS + h0);

    const float* eb = eall + (size_t)b * NL * NS;
    float4 e0 = *(const float4*)(eb + h0);
    float4 pr = *(const float4*)(priors + h0);
    float4 vres = make_float4(e0.x + pr.x, e0.y + pr.y, e0.z + pr.z, e0.w + pr.w);
    *(float4*)(A + h0) = vres;
    float4 e_cur = *(const float4*)(eb + NS + h0);   // e for l=1
    __syncthreads();                                 // full drain ONCE

    float* prev = A;
    float* cur = Bv;
    for (int l = 1; l < NL; ++l) {
        // fire-and-forget store of step l-1's result
        *(float4*)(out + ((size_t)(l - 1) * NB + b) * NS + h0) = vres;
        // prefetch next step's e quad (waited on use, next iteration)
        float4 e_nxt = make_float4(0.f, 0.f, 0.f, 0.f);
        if (l + 1 < NL) e_nxt = *(const float4*)(eb + (size_t)(l + 1) * NS + h0);

        // 5 b128 + 2 b32 LDS reads cover all four states' neighbor sets
        float4 c  = *(const float4*)(prev + h0);          // self quad
        float  xl = prev[h0 - 1];
        float  xr = prev[h0 + 4];
        float4 ym = *(const float4*)(prev + h0 - 16);
        float4 yp = *(const float4*)(prev + h0 + 16);
        float4 z1 = *(const float4*)(prev + h0 + 256);
        float4 z2 = *(const float4*)(prev + h0 + 512);

        // j=0: self=c.x, x+1=c.y, x-1=xl
        float r0 = lse7(w[0].x + c.x, w[1].x + c.y, w[2].x + xl,
                        w[3].x + yp.x, w[4].x + ym.x, w[5].x + z1.x, w[6].x + z2.x);
        // j=1: self=c.y, x+1=c.z, x-1=c.x
        float r1 = lse7(w[0].y + c.y, w[1].y + c.z, w[2].y + c.x,
                        w[3].y + yp.y, w[4].y + ym.y, w[5].y + z1.y, w[6].y + z2.y);
        // j=2: self=c.z, x+1=c.w, x-1=c.y
        float r2 = lse7(w[0].z + c.z, w[1].z + c.w, w[2].z + c.y,
                        w[3].z + yp.z, w[4].z + ym.z, w[5].z + z1.z, w[6].z + z2.z);
        // j=3: self=c.w, x+1=xr, x-1=c.z
        float r3 = lse7(w[0].w + c.w, w[1].w + xr, w[2].w + c.z,
                        w[3].w + yp.w, w[4].w + ym.w, w[5].w + z1.w, w[6].w + z2.w);

        vres = make_float4(e_cur.x + r0, e_cur.y + r1, e_cur.z + r2, e_cur.w + r3);
        *(float4*)(cur + h0) = vres;

        // LDS-only barrier: my ds_write retired -> signal -> writes visible
        __builtin_amdgcn_sched_barrier(0);
        asm volatile("s_waitcnt lgkmcnt(0)" ::: "memory");
        __builtin_amdgcn_s_barrier();
        __builtin_amdgcn_sched_barrier(0);

        e_cur = e_nxt;
        float* tmp = prev; prev = cur; cur = tmp;
    }

    // final step's result
    *(float4*)(out + ((size_t)(NL - 1) * NB + b) * NS + h0) = vres;
}

// ---------------------------------------------------------------------------
extern "C" void kernel_launch(void* const* d_in, const int* in_sizes, int n_in,
                              void* d_out, int out_size, void* d_ws, size_t ws_size,
                              hipStream_t stream) {
    (void)in_sizes; (void)n_in; (void)out_size; (void)ws_size;
    const int* stories  = (const int*)d_in[0];
    // d_in[1] = story_length (== NL), unused
    const float* priors = (const float*)d_in[2];
    const float* trans  = (const float*)d_in[3];
    const float* em     = (const float*)d_in[4];
    float* out = (float*)d_out;

    float* emT  = (float*)d_ws;                    // [NT][NS]    16 MB
    float* eall = emT + (size_t)NT * NS;           // [NB*NL][NS]  2 MB
    float* wtab = eall + (size_t)NB * NL * NS;     // [7][NS]     57 KB

    // grid y: 0..7 = smooth z-slices, 8 = wtab prep
    k_smooth<<<dim3(NT / TT, NZ + 1), 256, 0, stream>>>(em, emT, trans, wtab);
    k_eall<<<dim3(NB * NL, 2), 256, 0, stream>>>(stories, emT, eall);
    k_forward<<<dim3(NB), 512, 0, stream>>>(wtab, priors, eall, out);
}

// Round 13
// 37.002 us; speedup vs baseline: 1.1380x; 1.0583x over previous
//
#include <hip/hip_runtime.h>

// Problem constants (fixed by the reference)
#define NXY   16
#define NZ    8
#define NS    2048      // states = 16*16*8
#define NT    2048      // tokens
#define NB    16        // stories
#define NL    16        // story length
#define NSENT 16        // tokens per sentence
#define NEGV  (-1e9f)

// ---------------------------------------------------------------------------
// K1 v3: fused smoothing + transpose (round-6 proven body) PLUS the wtab
// prep (round-10 proven body) as extra grid blocks (blockIdx.y == 8).
// (round-12 proven, unchanged)
// ---------------------------------------------------------------------------
#define TT   16
#define SPAD 17

__global__ __launch_bounds__(256) void k_smooth(const float* __restrict__ em,
                                                float* __restrict__ emT,
                                                const float* __restrict__ trans,
                                                float* __restrict__ wtab) {
    const int tid = threadIdx.x;

    if (blockIdx.y == NZ) {
        // ---- prep path: one thread per (neighbor-slot, state)
        const int g = blockIdx.x * 256 + tid;          // [0, 32768)
        if (g < 7 * NS) {
            const int k = g >> 11;
            const int h = g & (NS - 1);
            const int x = h & 15, y = (h >> 4) & 15, z = h >> 8;
            const float* row = trans + (size_t)h * NS;
            float w;
            switch (k) {
                case 0: w = row[h]; break;
                case 1: w = (x < 15) ? row[h + 1]   : NEGV; break;
                case 2: w = (x > 0)  ? row[h - 1]   : NEGV; break;
                case 3: w = (y < 15) ? row[h + 16]  : NEGV; break;
                case 4: w = (y > 0)  ? row[h - 16]  : NEGV; break;
                case 5: w = (z < 7)  ? row[h + 256] : NEGV; break;
                default: w = (z < 6) ? row[h + 512] : NEGV; break;
            }
            wtab[g] = w;
        }
        return;
    }

    // ---- smooth path (round-6 body, unchanged)
    __shared__ float S[256 * SPAD];   // 17408 B
    const int t0 = blockIdx.x * TT;
    const int z = blockIdx.y;
    const int toff = tid & 15, y = tid >> 4;

    const float* base = em + ((size_t)z * 256 + y * 16) * NT + t0 + toff;
    float ex[16];
#pragma unroll
    for (int x = 0; x < 16; ++x)
        ex[x] = __expf(base[(size_t)x * NT]);

#pragma unroll
    for (int x = 0; x < 16; ++x) {
        const int xm2 = x - 2 < 0 ? 0 : x - 2, xm1 = x - 1 < 0 ? 0 : x - 1;
        const int xp1 = x + 1 > 15 ? 15 : x + 1, xp2 = x + 2 > 15 ? 15 : x + 2;
        S[(y * 16 + x) * SPAD + toff] = ex[xm2] + ex[xm1] + ex[x] + ex[xp1] + ex[xp2];
    }
    __syncthreads();

    const int x2 = tid & 15, y2 = tid >> 4;
    int ry[5];
#pragma unroll
    for (int k = 0; k < 5; ++k) {
        int yy = y2 + k - 2; yy = yy < 0 ? 0 : (yy > 15 ? 15 : yy);
        ry[k] = (yy * 16 + x2) * SPAD;
    }
    const float LOG25 = 3.2188758248682006f;   // log(5)+log(5)
    float* ob = emT + (size_t)t0 * NS + z * 256 + tid;
#pragma unroll
    for (int t = 0; t < TT; ++t) {
        float a = S[ry[0] + t] + S[ry[1] + t] + S[ry[2] + t] + S[ry[3] + t] + S[ry[4] + t];
        ob[(size_t)t * NS] = __logf(a) - LOG25;
    }
}

// ---------------------------------------------------------------------------
// K2: e_all[b,l,s] = sum_j em_T[tok[b,l,j], s]   (round-2 proven, unchanged)
// ---------------------------------------------------------------------------
__global__ __launch_bounds__(256) void k_eall(const int* __restrict__ stories,
                                              const float* __restrict__ emT,
                                              float* __restrict__ eall) {
    const int bl = blockIdx.x;
    const int col = blockIdx.y * 256 + threadIdx.x;
    __shared__ int toks[NSENT];
    if (threadIdx.x < NSENT) toks[threadIdx.x] = stories[bl * NSENT + threadIdx.x];
    __syncthreads();

    float4 a = make_float4(0.f, 0.f, 0.f, 0.f);
#pragma unroll 4
    for (int j = 0; j < NSENT; ++j) {
        float4 v = ((const float4*)(emT + (size_t)toks[j] * NS))[col];
        a.x += v.x; a.y += v.y; a.z += v.z; a.w += v.w;
    }
    ((float4*)(eall + (size_t)bl * NS))[col] = a;
}

// ---------------------------------------------------------------------------
// K3 v7: the EXACT round-2 proven forward body (1024 threads x 2 states,
// scalar clamped-index LDS reads, plain __syncthreads, in-loop e-loads and
// out-stores) with ONE change: weights come from the compact wtab
// (coalesced reads, written by the fused prep) instead of the 300KB/block
// scattered trans gather. Decisive A/B vs the v4-v6 body lineage.
// ---------------------------------------------------------------------------
__global__ __launch_bounds__(1024) void k_forward(const float* __restrict__ wtab,
                                                  const float* __restrict__ priors,
                                                  const float* __restrict__ eall,
                                                  float* __restrict__ out) {
    __shared__ float buf0[NS];
    __shared__ float buf1[NS];
    const int b = blockIdx.x;
    const int tid = threadIdx.x;

    float wr[2][7];
    int   ix[2][7];
#pragma unroll
    for (int p = 0; p < 2; ++p) {
        const int h = tid + p * 1024;
        const int x = h & 15, y = (h >> 4) & 15, z = h >> 8;
        wr[p][0] = wtab[0 * NS + h];  ix[p][0] = h;
        wr[p][1] = wtab[1 * NS + h];  ix[p][1] = (x < 15) ? h + 1   : h;
        wr[p][2] = wtab[2 * NS + h];  ix[p][2] = (x > 0)  ? h - 1   : h;
        wr[p][3] = wtab[3 * NS + h];  ix[p][3] = (y < 15) ? h + 16  : h;
        wr[p][4] = wtab[4 * NS + h];  ix[p][4] = (y > 0)  ? h - 16  : h;
        wr[p][5] = wtab[5 * NS + h];  ix[p][5] = (z < 7)  ? h + 256 : h;
        wr[p][6] = wtab[6 * NS + h];  ix[p][6] = (z < 6)  ? h + 512 : h;
        float v = eall[(size_t)b * NL * NS + h] + priors[h];
        buf0[h] = v;
        out[(size_t)b * NS + h] = v;
    }
    __syncthreads();

    float* prev = buf0;
    float* cur = buf1;
    for (int l = 1; l < NL; ++l) {
        const float* e = eall + ((size_t)b * NL + l) * NS;
#pragma unroll
        for (int p = 0; p < 2; ++p) {
            const int h = tid + p * 1024;
            float v0 = wr[p][0] + prev[ix[p][0]];
            float v1 = wr[p][1] + prev[ix[p][1]];
            float v2 = wr[p][2] + prev[ix[p][2]];
            float v3 = wr[p][3] + prev[ix[p][3]];
            float v4 = wr[p][4] + prev[ix[p][4]];
            float v5 = wr[p][5] + prev[ix[p][5]];
            float v6 = wr[p][6] + prev[ix[p][6]];
            float m = fmaxf(fmaxf(fmaxf(v0, v1), fmaxf(v2, v3)),
                            fmaxf(fmaxf(v4, v5), v6));
            float s = __expf(v0 - m) + __expf(v1 - m) + __expf(v2 - m) + __expf(v3 - m) +
                      __expf(v4 - m) + __expf(v5 - m) + __expf(v6 - m);
            float v = e[h] + m + __logf(s);
            cur[h] = v;
            out[((size_t)l * NB + b) * NS + h] = v;
        }
        __syncthreads();
        float* tmp = prev; prev = cur; cur = tmp;
    }
}

// ---------------------------------------------------------------------------
extern "C" void kernel_launch(void* const* d_in, const int* in_sizes, int n_in,
                              void* d_out, int out_size, void* d_ws, size_t ws_size,
                              hipStream_t stream) {
    (void)in_sizes; (void)n_in; (void)out_size; (void)ws_size;
    const int* stories  = (const int*)d_in[0];
    // d_in[1] = story_length (== NL), unused
    const float* priors = (const float*)d_in[2];
    const float* trans  = (const float*)d_in[3];
    const float* em     = (const float*)d_in[4];
    float* out = (float*)d_out;

    float* emT  = (float*)d_ws;                    // [NT][NS]    16 MB
    float* eall = emT + (size_t)NT * NS;           // [NB*NL][NS]  2 MB
    float* wtab = eall + (size_t)NB * NL * NS;     // [7][NS]     57 KB

    // grid y: 0..7 = smooth z-slices, 8 = wtab prep
    k_smooth<<<dim3(NT / TT, NZ + 1), 256, 0, stream>>>(em, emT, trans, wtab);
    k_eall<<<dim3(NB * NL, 2), 256, 0, stream>>>(stories, emT, eall);
    k_forward<<<dim3(NB), 1024, 0, stream>>>(wtab, priors, eall, out);
}